// Round 4
// baseline (598.847 us; speedup 1.0000x reference)
//
#include <hip/hip_runtime.h>
#include <cstddef>

#define BB 16
#define CC_ 64
#define HH 192
#define WW 192
#define HW2 4096
// padded channels-last x: [b][194][196][64], real data at rows 1..192, cols 1..192
#define XPH 194
#define XPW 196

typedef _Float16 f16x8 __attribute__((ext_vector_type(8)));
typedef float f32x4 __attribute__((ext_vector_type(4)));

// ---------------- Kernel W: pack wqk fp32 -> fp16 A-fragment layout --------
// wh[kc=(r*2+cihalf)][co 128][s*32 + ci%32]
__global__ __launch_bounds__(1024) void k_wpack(const float* __restrict__ wqk,
                                                _Float16* __restrict__ wh) {
  int e = blockIdx.x * 1024 + threadIdx.x;  // 72*1024 = 73728 = 128*576
  int co = e / 576, t = e % 576;
  int ci = t / 9, rs = t % 9;
  int r = rs / 3, s = rs % 3;
  int ch = ci >> 5, t32 = ci & 31;
  wh[(((r * 2 + ch) * 128 + co) * 96) + s * 32 + t32] = (_Float16)wqk[e];
}

// ---------------- Kernel XH: zero the halo of padded xh --------------------
__global__ __launch_bounds__(256) void k_xhalo(_Float16* __restrict__ xh) {
  int e = blockIdx.x * 256 + threadIdx.x;
  int b = e / 9280, i = e % 9280;
  int r, px, c;
  if (i < 3136) {
    r = (i < 1568) ? 0 : 193;
    int j = (i < 1568) ? i : i - 1568;
    px = j >> 3;
    c = j & 7;
  } else {
    int i2 = i - 3136;
    r = 1 + (i2 >> 5);
    int rem = i2 & 31;
    int sel = rem >> 3;
    px = (sel == 0) ? 0 : 192 + sel;  // 0,193,194,195
    c = rem & 7;
  }
  *(f16x8*)(xh + (((size_t)b * XPH + r) * XPW + px) * 64 + c * 8) =
      (f16x8)(_Float16)0;
}

// ---------------- Kernel X: x fp32 NCHW -> fp16 padded channels-last -------
__global__ __launch_bounds__(256) void k_xpack(const float* __restrict__ x,
                                               _Float16* __restrict__ xh) {
  int blk = blockIdx.x;
  int xg = blk % 3;
  int t = blk / 3;
  int y = t % 192, b = t / 192;
  int x0 = xg * 64;
  __shared__ _Float16 tl[64 * 72];  // [col][ci]
  int tid = threadIdx.x;
  int ci = tid >> 2, c4 = (tid & 3) * 16;
  const float* xp = x + ((size_t)(b * 64 + ci) * HH + y) * WW + x0 + c4;
#pragma unroll
  for (int i = 0; i < 4; ++i) {
    float4 v = *(const float4*)(xp + i * 4);
    tl[(c4 + i * 4 + 0) * 72 + ci] = (_Float16)v.x;
    tl[(c4 + i * 4 + 1) * 72 + ci] = (_Float16)v.y;
    tl[(c4 + i * 4 + 2) * 72 + ci] = (_Float16)v.z;
    tl[(c4 + i * 4 + 3) * 72 + ci] = (_Float16)v.w;
  }
  __syncthreads();
#pragma unroll
  for (int i = 0; i < 2; ++i) {
    int e = tid + 256 * i;
    int col = e >> 3, g = e & 7;
    *(f16x8*)(xh + (((size_t)b * XPH + y + 1) * XPW + x0 + 1 + col) * 64 + g * 8) =
        *(f16x8*)&tl[col * 72 + g * 8];
  }
}

// ---------------- Kernel 1: qk conv3x3 stride3, no-LDS MFMA implicit GEMM --
__global__ __launch_bounds__(256) void k_qkconv(const _Float16* __restrict__ xh,
                                                const _Float16* __restrict__ wh,
                                                _Float16* __restrict__ qkh) {
  int blk = blockIdx.x;
  int pt = blk & 31, b = blk >> 5;
  int tid = threadIdx.x;
  int w = tid >> 6, lane = tid & 63, n16 = lane & 15, quad = lane >> 4;
  int mh = w & 1, nh = w >> 1;
  const _Float16* xb = xh + (size_t)b * (XPH * XPW * 64);

  f32x4 acc[4][4];
#pragma unroll
  for (int mt = 0; mt < 4; ++mt)
#pragma unroll
    for (int nt = 0; nt < 4; ++nt) acc[mt][nt] = (f32x4){0.f, 0.f, 0.f, 0.f};

#pragma unroll
  for (int kc = 0; kc < 6; ++kc) {
    int r = kc >> 1, ch = kc & 1;
    int irow = 6 * pt + 3 * nh + r;
    const _Float16* wp = wh + (size_t)kc * (128 * 96);
#pragma unroll
    for (int s = 0; s < 3; ++s) {
      f16x8 af[4], bf[4];
#pragma unroll
      for (int mt = 0; mt < 4; ++mt)
        af[mt] = *(const f16x8*)(wp + (mh * 64 + mt * 16 + n16) * 96 + s * 32 +
                                 quad * 8);
#pragma unroll
      for (int nt = 0; nt < 4; ++nt) {
        int col = 3 * (nt * 16 + n16) + s;
        bf[nt] = *(const f16x8*)(xb + ((size_t)(irow + 1) * XPW + col + 1) * 64 +
                                 ch * 32 + quad * 8);
      }
#pragma unroll
      for (int mt = 0; mt < 4; ++mt)
#pragma unroll
        for (int nt = 0; nt < 4; ++nt)
          acc[mt][nt] = __builtin_amdgcn_mfma_f32_16x16x32_f16(af[mt], bf[nt],
                                                               acc[mt][nt], 0, 0, 0);
    }
  }
  int py = pt * 2 + nh;
#pragma unroll
  for (int mt = 0; mt < 4; ++mt)
#pragma unroll
    for (int reg = 0; reg < 4; ++reg) {
      int co = mh * 64 + mt * 16 + quad * 4 + reg;
      _Float16* op = qkh + (size_t)(b * 128 + co) * HW2 + py * 64;
#pragma unroll
      for (int nt = 0; nt < 4; ++nt) op[nt * 16 + n16] = (_Float16)acc[mt][nt][reg];
    }
}

// ---------------- Kernel Q: build padded shifted q copies ------------------
// qpad[b][djx][ci][68][64]: row-pad 2, col pre-shifted by dj=djx-2, zero-fill.
__global__ __launch_bounds__(256) void k_qpad(const _Float16* __restrict__ qkh,
                                              _Float16* __restrict__ qpad) {
  int blk = blockIdx.x;  // 1024 = b*64+ci
  int b = blk >> 6, ci = blk & 63;
  __shared__ _Float16 qrow[4096];
  int tid = threadIdx.x;
  const _Float16* src = qkh + (size_t)(b * 128 + ci) * HW2;
#pragma unroll
  for (int i = 0; i < 2; ++i)
    ((f16x8*)qrow)[tid + 256 * i] = ((const f16x8*)src)[tid + 256 * i];
  __syncthreads();
  _Float16* dst = qpad + ((size_t)(b * 5) * 64 + ci) * 4352;
  const f16x8 zero = (f16x8)(_Float16)0;
  for (int it = tid; it < 544; it += 256) {  // 68 rows x 8 w8
    int w8 = it & 7, hr = it >> 3;
    int h = hr - 2;
    bool rowok = (unsigned)h < 64u;
    f16x8 vm = (rowok && w8 > 0) ? *(const f16x8*)&qrow[h * 64 + w8 * 8 - 8] : zero;
    f16x8 vc = rowok ? *(const f16x8*)&qrow[h * 64 + w8 * 8] : zero;
    f16x8 vp = (rowok && w8 < 7) ? *(const f16x8*)&qrow[h * 64 + w8 * 8 + 8] : zero;
#pragma unroll
    for (int djx = 0; djx < 5; ++djx) {
      const int s = djx - 2;
      f16x8 r;
#pragma unroll
      for (int j = 0; j < 8; ++j) {
        const int rel = j + s;
        r[j] = (rel < 0) ? vm[8 + rel] : ((rel < 8) ? vc[rel] : vp[rel - 8]);
      }
      *(f16x8*)(dst + (size_t)djx * (64 * 4352) + hr * 64 + w8 * 8) = r;
    }
  }
}

// ---------------- Kernel 2: attn via MFMA, ZERO global atomics -------------
// grid 400 = XCD-swizzled (b, sh); block 512 = 8 waves = 4 co-groups x 2
// K-halves. Each wave: 16co x 64ci over K=2048, depth-4 register prefetch.
// The two K-half partials merge through 16KB LDS with ONE barrier; each
// attn_p element is written exactly once by a plain store (no memset, no
// atomics -- r0-r3 all sat at ~130-145us on merge-path costs).
__global__ __launch_bounds__(512) void k_attn(const _Float16* __restrict__ qkh,
                                              const _Float16* __restrict__ qpad,
                                              float* __restrict__ attn_p) {
  int blk = blockIdx.x;
  int xcd = blk & 7, j = blk >> 3;  // j 0..49
  int b = xcd + ((j >= 25) ? 8 : 0);
  int sh = (j >= 25) ? (j - 25) : j;  // 0..24
  int djx = sh % 5, dix = sh / 5;
  int tid = threadIdx.x, w = tid >> 6, lane = tid & 63;
  int n16 = lane & 15, quad = lane >> 4;
  int g = w >> 1, h = w & 1;  // co-group, K-half

  __shared__ float lpart[4096];  // [g][co16][ci64]

  const _Float16* ka = qkh + (size_t)(b * 128 + 64 + g * 16 + n16) * HW2 +
                       h * 2048 + quad * 8;
  const _Float16* qa = qpad + ((size_t)(b * 5 + djx) * 64 + n16) * 4352 +
                       dix * 64 + h * 2048 + quad * 8;

  f32x4 acc[4];
#pragma unroll
  for (int nt = 0; nt < 4; ++nt) acc[nt] = (f32x4){0.f, 0.f, 0.f, 0.f};

  f16x8 afS[4], bfS[4][4];
#define LDSLOT(sl, k_)                                                         \
  {                                                                            \
    afS[sl] = *(const f16x8*)(ka + (k_)*32);                                   \
    _Pragma("unroll") for (int nt = 0; nt < 4; ++nt) bfS[sl][nt] =             \
        *(const f16x8*)(qa + (size_t)nt * 69632 + (k_)*32);                    \
  }
  LDSLOT(0, 0) LDSLOT(1, 1) LDSLOT(2, 2) LDSLOT(3, 3)

#pragma unroll
  for (int ks = 0; ks < 64; ++ks) {
    const int sl = ks & 3;
#pragma unroll
    for (int nt = 0; nt < 4; ++nt)
      acc[nt] = __builtin_amdgcn_mfma_f32_16x16x32_f16(afS[sl], bfS[sl][nt],
                                                       acc[nt], 0, 0, 0);
    if (ks + 4 < 64) LDSLOT(sl, ks + 4)
  }
#undef LDSLOT

  if (h == 0) {
#pragma unroll
    for (int nt = 0; nt < 4; ++nt)
#pragma unroll
      for (int reg = 0; reg < 4; ++reg)
        lpart[(g * 16 + quad * 4 + reg) * 64 + nt * 16 + n16] = acc[nt][reg];
  }
  __syncthreads();
  if (h == 1) {
    float* op = attn_p + (size_t)(b * 25 + sh) * 4096;
#pragma unroll
    for (int nt = 0; nt < 4; ++nt)
#pragma unroll
      for (int reg = 0; reg < 4; ++reg) {
        int idx = (g * 16 + quad * 4 + reg) * 64 + nt * 16 + n16;
        op[idx] = lpart[idx] + acc[nt][reg];
      }
  }
}

// ---------------- Kernel 3: ak_t = valid-conv(attn, weight) ----------------
__global__ __launch_bounds__(576) void k_akconv(const float* __restrict__ attn_p,
                                                const float* __restrict__ wgt,
                                                float* __restrict__ akt) {
  int blk = blockIdx.x;
  int b = blk >> 6, co = blk & 63;
  __shared__ float sa[64 * 25];
  int tid = threadIdx.x;
  for (int e = tid; e < 1600; e += 576) {
    int didj = e >> 6, ci = e & 63;
    size_t idx = (((size_t)b * 25 + didj) * 64 + co) * 64 + ci;
    sa[ci * 25 + didj] = attn_p[idx];
  }
  __syncthreads();
  int o = tid / 9, rs = tid % 9;
  int ki = rs / 3, kj = rs % 3;
  float acc = 0.f;
  for (int ci = 0; ci < 64; ++ci) {
    const float* wp = wgt + (o * 64 + ci) * 9;
    const float* ap = sa + ci * 25 + ki * 5 + kj;
#pragma unroll
    for (int r = 0; r < 3; ++r)
#pragma unroll
      for (int s = 0; s < 3; ++s) acc += ap[r * 5 + s] * wp[r * 3 + s];
  }
  akt[((size_t)(b * 64 + o) * 64 + co) * 9 + rs] = acc;
}

// ---------------- Kernel 4: per-(b,o) norm + fp16 kern assembly ------------
__global__ __launch_bounds__(576) void k_kern(const float* __restrict__ akt,
                                              const float* __restrict__ wgt,
                                              const float* __restrict__ temp,
                                              _Float16* __restrict__ kh) {
  int blk = blockIdx.x;
  int o = blk & 63;
  int tid = threadIdx.x;
  float v = akt[(size_t)blk * 576 + tid];
  float sq = v * v;
#pragma unroll
  for (int m = 1; m < 64; m <<= 1) sq += __shfl_xor(sq, m, 64);
  __shared__ float wsum[9];
  if ((tid & 63) == 0) wsum[tid >> 6] = sq;
  __syncthreads();
  float tot = 0.f;
#pragma unroll
  for (int i = 0; i < 9; ++i) tot += wsum[i];
  float inv = temp[0] / fmaxf(sqrtf(tot), 1e-12f);
  float kv = wgt[o * 576 + tid] + v * inv;
  int b = blk >> 6;
  int ci = tid / 9, rs = tid % 9;
  kh[(((size_t)(b * 9 + rs) * 64 + o) * 64) + ci] = (_Float16)kv;
}

// ---------------- Kernel 5: dynamic 3x3 conv + ReLU, LDS-staged x tile -----
__global__ __launch_bounds__(256, 3) void k_final(const _Float16* __restrict__ xh,
                                                  const _Float16* __restrict__ kh,
                                                  float* __restrict__ out) {
  int blk = blockIdx.x;
  int xt = blk % 3;
  int t2 = blk / 3;
  int yt = t2 % 48, b = t2 / 48;
  int y0 = yt * 4, x0 = xt * 64;

  __shared__ __align__(16) _Float16 xs[6 * 68 * 64];  // 52,224 B -> 3 blocks/CU

  int tid = threadIdx.x;
  int w = tid >> 6, lane = tid & 63;
  int n16 = lane & 15, quad = lane >> 4;

  const _Float16* xb = xh + (size_t)b * (XPH * XPW * 64);
  const _Float16* kb = kh + (size_t)b * (9 * 64 * 64);

  {
    f16x8 v[13];
#pragma unroll
    for (int i = 0; i < 13; ++i) {
      int e = tid + 256 * i;
      if (e < 3264) {
        int row = e / 544, rem = e % 544;
        int px = rem >> 3, c = rem & 7;
        v[i] = *(const f16x8*)(xb + ((size_t)(y0 + row) * XPW + x0 + px) * 64 +
                               c * 8);
      }
    }
#pragma unroll
    for (int i = 0; i < 13; ++i) {
      int e = tid + 256 * i;
      if (e < 3264) {
        int row = e / 544, rem = e % 544;
        int px = rem >> 3, c = rem & 7;
        *(f16x8*)&xs[((row * 68 + px) * 8 + (c ^ (px & 7))) * 8] = v[i];
      }
    }
  }
  __syncthreads();

  f32x4 acc[4][4];
#pragma unroll
  for (int mt = 0; mt < 4; ++mt)
#pragma unroll
    for (int nt = 0; nt < 4; ++nt) acc[mt][nt] = (f32x4){0.f, 0.f, 0.f, 0.f};

#define LDAF(dst, ch_)                                                          \
  {                                                                             \
    const int rs_ = (ch_) >> 1, hi_ = (ch_)&1;                                  \
    _Pragma("unroll") for (int mt = 0; mt < 4; ++mt) dst[mt] =                  \
        *(const f16x8*)(kb + ((size_t)rs_ * 64 + mt * 16 + n16) * 64 +          \
                        hi_ * 32 + quad * 8);                                   \
  }

  f16x8 af[3][4];
  LDAF(af[0], 0)
  LDAF(af[1], 1)

#pragma unroll
  for (int ch = 0; ch < 18; ++ch) {
    if (ch + 2 < 18) LDAF(af[(ch + 2) % 3], ch + 2)
    int rs = ch >> 1, hi = ch & 1;
    int r = rs / 3, s = rs % 3;
    int trow = w + r;  // tile row 0..5
    f16x8 bf[4];
#pragma unroll
    for (int nt = 0; nt < 4; ++nt) {
      int px = nt * 16 + n16 + s;  // 0..65
      int c = (hi * 4 + quad) ^ (px & 7);
      bf[nt] = *(const f16x8*)&xs[((trow * 68 + px) * 8 + c) * 8];
    }
#pragma unroll
    for (int mt = 0; mt < 4; ++mt)
#pragma unroll
      for (int nt = 0; nt < 4; ++nt)
        acc[mt][nt] = __builtin_amdgcn_mfma_f32_16x16x32_f16(af[ch % 3][mt],
                                                             bf[nt], acc[mt][nt],
                                                             0, 0, 0);
  }
#undef LDAF

  int y = y0 + w;
#pragma unroll
  for (int mt = 0; mt < 4; ++mt)
#pragma unroll
    for (int reg = 0; reg < 4; ++reg) {
      int o = mt * 16 + quad * 4 + reg;
      float* op = out + (((size_t)(b * 64 + o) * HH + y) * WW + x0);
#pragma unroll
      for (int nt = 0; nt < 4; ++nt)
        op[nt * 16 + n16] = fmaxf(acc[mt][nt][reg], 0.f);
    }
}

extern "C" void kernel_launch(void* const* d_in, const int* in_sizes, int n_in,
                              void* d_out, int out_size, void* d_ws, size_t ws_size,
                              hipStream_t stream) {
  const float* x = (const float*)d_in[0];     // (16,64,192,192)
  const float* wqk = (const float*)d_in[1];   // (128,64,3,3)
  const float* wgt = (const float*)d_in[2];   // (64,64,3,3)
  const float* temp = (const float*)d_in[3];  // (1,1,1)
  float* out = (float*)d_out;
  char* ws = (char*)d_ws;

  // Workspace layout (bytes):
  _Float16* xh = (_Float16*)ws;                        // 77,873,152 (16*194*196*64*2)
  _Float16* qkh = (_Float16*)(ws + 77873152);          // 16,777,216
  _Float16* qpad = (_Float16*)(ws + 94650368);         // 44,564,480
  float* attn_p = (float*)(ws + 139214848);            //  6,553,600 (write-once)
  // wh aliases the qpad tail: dead before k_qpad writes qpad.
  _Float16* wh = (_Float16*)(ws + 139067392);          //    147,456
  // akt/kh alias the qpad head (qpad dead after k_attn):
  float* akt = (float*)(ws + 94650368);                //  2,359,296
  _Float16* kh = (_Float16*)(ws + 97009664);           //  1,179,648
  // total 145,768,448 B (~145.8 MB)

  k_wpack<<<dim3(72), 1024, 0, stream>>>(wqk, wh);
  k_xhalo<<<dim3(580), 256, 0, stream>>>(xh);
  k_xpack<<<dim3(9216), 256, 0, stream>>>(x, xh);
  k_qkconv<<<dim3(512), 256, 0, stream>>>(xh, wh, qkh);
  k_qpad<<<dim3(1024), 256, 0, stream>>>(qkh, qpad);
  k_attn<<<dim3(400), 512, 0, stream>>>(qkh, qpad, attn_p);
  k_akconv<<<dim3(1024), 576, 0, stream>>>(attn_p, wgt, akt);
  k_kern<<<dim3(1024), 576, 0, stream>>>(akt, wgt, temp, kh);
  k_final<<<dim3(2304), 256, 0, stream>>>(xh, kh, out);
}

// Round 5
// 493.017 us; speedup vs baseline: 1.2147x; 1.2147x over previous
//
#include <hip/hip_runtime.h>
#include <cstddef>

#define BB 16
#define CC_ 64
#define HH 192
#define WW 192
#define HW2 4096
// padded channels-last x: [b][194][196][64], real data at rows 1..192, cols 1..192
#define XPH 194
#define XPW 196

typedef _Float16 f16x8 __attribute__((ext_vector_type(8)));
typedef float f32x4 __attribute__((ext_vector_type(4)));

// ---------------- Kernel W: pack wqk fp32 -> fp16 A-fragment layout --------
// wh[kc=(r*2+cihalf)][co 128][s*32 + ci%32]
__global__ __launch_bounds__(1024) void k_wpack(const float* __restrict__ wqk,
                                                _Float16* __restrict__ wh) {
  int e = blockIdx.x * 1024 + threadIdx.x;  // 72*1024 = 73728 = 128*576
  int co = e / 576, t = e % 576;
  int ci = t / 9, rs = t % 9;
  int r = rs / 3, s = rs % 3;
  int ch = ci >> 5, t32 = ci & 31;
  wh[(((r * 2 + ch) * 128 + co) * 96) + s * 32 + t32] = (_Float16)wqk[e];
}

// ---------------- Kernel XH: zero the halo of padded xh --------------------
__global__ __launch_bounds__(256) void k_xhalo(_Float16* __restrict__ xh) {
  int e = blockIdx.x * 256 + threadIdx.x;
  int b = e / 9280, i = e % 9280;
  int r, px, c;
  if (i < 3136) {
    r = (i < 1568) ? 0 : 193;
    int j = (i < 1568) ? i : i - 1568;
    px = j >> 3;
    c = j & 7;
  } else {
    int i2 = i - 3136;
    r = 1 + (i2 >> 5);
    int rem = i2 & 31;
    int sel = rem >> 3;
    px = (sel == 0) ? 0 : 192 + sel;  // 0,193,194,195
    c = rem & 7;
  }
  *(f16x8*)(xh + (((size_t)b * XPH + r) * XPW + px) * 64 + c * 8) =
      (f16x8)(_Float16)0;
}

// ---------------- Kernel X: x fp32 NCHW -> fp16 padded channels-last -------
__global__ __launch_bounds__(256) void k_xpack(const float* __restrict__ x,
                                               _Float16* __restrict__ xh) {
  int blk = blockIdx.x;
  int xg = blk % 3;
  int t = blk / 3;
  int y = t % 192, b = t / 192;
  int x0 = xg * 64;
  __shared__ _Float16 tl[64 * 72];  // [col][ci]
  int tid = threadIdx.x;
  int ci = tid >> 2, c4 = (tid & 3) * 16;
  const float* xp = x + ((size_t)(b * 64 + ci) * HH + y) * WW + x0 + c4;
#pragma unroll
  for (int i = 0; i < 4; ++i) {
    float4 v = *(const float4*)(xp + i * 4);
    tl[(c4 + i * 4 + 0) * 72 + ci] = (_Float16)v.x;
    tl[(c4 + i * 4 + 1) * 72 + ci] = (_Float16)v.y;
    tl[(c4 + i * 4 + 2) * 72 + ci] = (_Float16)v.z;
    tl[(c4 + i * 4 + 3) * 72 + ci] = (_Float16)v.w;
  }
  __syncthreads();
#pragma unroll
  for (int i = 0; i < 2; ++i) {
    int e = tid + 256 * i;
    int col = e >> 3, g = e & 7;
    *(f16x8*)(xh + (((size_t)b * XPH + y + 1) * XPW + x0 + 1 + col) * 64 + g * 8) =
        *(f16x8*)&tl[col * 72 + g * 8];
  }
}

// ---------------- Kernel 1: qk conv3x3 stride3, no-LDS MFMA implicit GEMM --
// q-half (co 0..63): stored row-major as before (k_qpad consumes it).
// k-half (co 64..127): repacked via LDS into frag-major ka2 layout
//   ka2[b][g 4][s' 128][lane 64][8]  (same memory as the old qkh k-half) so
//   k_attn's A-frag loads are contiguous 1KB per wave-instruction.
__global__ __launch_bounds__(256) void k_qkconv(const _Float16* __restrict__ xh,
                                                const _Float16* __restrict__ wh,
                                                _Float16* __restrict__ qkh) {
  int blk = blockIdx.x;
  int pt = blk & 31, b = blk >> 5;
  int tid = threadIdx.x;
  int w = tid >> 6, lane = tid & 63, n16 = lane & 15, quad = lane >> 4;
  int mh = w & 1, nh = w >> 1;
  const _Float16* xb = xh + (size_t)b * (XPH * XPW * 64);

  __shared__ _Float16 lds_k[16 * 64 * 8];  // 16 KB repack buffer

  f32x4 acc[4][4];
#pragma unroll
  for (int mt = 0; mt < 4; ++mt)
#pragma unroll
    for (int nt = 0; nt < 4; ++nt) acc[mt][nt] = (f32x4){0.f, 0.f, 0.f, 0.f};

#pragma unroll
  for (int kc = 0; kc < 6; ++kc) {
    int r = kc >> 1, ch = kc & 1;
    int irow = 6 * pt + 3 * nh + r;
    const _Float16* wp = wh + (size_t)kc * (128 * 96);
#pragma unroll
    for (int s = 0; s < 3; ++s) {
      f16x8 af[4], bf[4];
#pragma unroll
      for (int mt = 0; mt < 4; ++mt)
        af[mt] = *(const f16x8*)(wp + (mh * 64 + mt * 16 + n16) * 96 + s * 32 +
                                 quad * 8);
#pragma unroll
      for (int nt = 0; nt < 4; ++nt) {
        int col = 3 * (nt * 16 + n16) + s;
        bf[nt] = *(const f16x8*)(xb + ((size_t)(irow + 1) * XPW + col + 1) * 64 +
                                 ch * 32 + quad * 8);
      }
#pragma unroll
      for (int mt = 0; mt < 4; ++mt)
#pragma unroll
        for (int nt = 0; nt < 4; ++nt)
          acc[mt][nt] = __builtin_amdgcn_mfma_f32_16x16x32_f16(af[mt], bf[nt],
                                                               acc[mt][nt], 0, 0, 0);
    }
  }
  int py = pt * 2 + nh;
  if (mh == 0) {
    // q rows: unchanged row-major store
#pragma unroll
    for (int mt = 0; mt < 4; ++mt)
#pragma unroll
      for (int reg = 0; reg < 4; ++reg) {
        int co = mt * 16 + quad * 4 + reg;
        _Float16* op = qkh + (size_t)(b * 128 + co) * HW2 + py * 64;
#pragma unroll
        for (int nt = 0; nt < 4; ++nt) op[nt * 16 + n16] = (_Float16)acc[mt][nt][reg];
      }
  } else {
    // k rows: scatter into LDS in ka2 order (p_local = nh*64 + nt*16 + n16)
#pragma unroll
    for (int mt = 0; mt < 4; ++mt)
#pragma unroll
      for (int nt = 0; nt < 4; ++nt)
#pragma unroll
        for (int reg = 0; reg < 4; ++reg) {
          int plocal = nh * 64 + nt * 16 + n16;
          int tile = mt * 4 + (plocal >> 5);
          int lanep = ((plocal >> 3) & 3) * 16 + quad * 4 + reg;
          lds_k[(tile * 64 + lanep) * 8 + (plocal & 7)] = (_Float16)acc[mt][nt][reg];
        }
  }
  __syncthreads();
  // coalesced readout: 16 tiles x 1KB -> ka2 (lives in the old qkh k-half)
  _Float16* ka2b = qkh + (size_t)(b * 128 + 64) * HW2;
#pragma unroll
  for (int r = 0; r < 4; ++r) {
    int e = tid + 256 * r;
    int tile = e >> 6, lanep = e & 63;
    int g = tile >> 2, sp = pt * 4 + (tile & 3);
    *(f16x8*)(ka2b + ((size_t)(g * 128 + sp) * 64 + lanep) * 8) =
        *(f16x8*)&lds_k[e * 8];
  }
}

// ---------------- Kernel Q: build padded shifted q copies ------------------
// qpad[b][djx][ci][68][64]: row-pad 2, col pre-shifted by dj=djx-2, zero-fill.
__global__ __launch_bounds__(256) void k_qpad(const _Float16* __restrict__ qkh,
                                              _Float16* __restrict__ qpad) {
  int blk = blockIdx.x;  // 1024 = b*64+ci
  int b = blk >> 6, ci = blk & 63;
  __shared__ _Float16 qrow[4096];
  int tid = threadIdx.x;
  const _Float16* src = qkh + (size_t)(b * 128 + ci) * HW2;
#pragma unroll
  for (int i = 0; i < 2; ++i)
    ((f16x8*)qrow)[tid + 256 * i] = ((const f16x8*)src)[tid + 256 * i];
  __syncthreads();
  _Float16* dst = qpad + ((size_t)(b * 5) * 64 + ci) * 4352;
  const f16x8 zero = (f16x8)(_Float16)0;
  for (int it = tid; it < 544; it += 256) {  // 68 rows x 8 w8
    int w8 = it & 7, hr = it >> 3;
    int h = hr - 2;
    bool rowok = (unsigned)h < 64u;
    f16x8 vm = (rowok && w8 > 0) ? *(const f16x8*)&qrow[h * 64 + w8 * 8 - 8] : zero;
    f16x8 vc = rowok ? *(const f16x8*)&qrow[h * 64 + w8 * 8] : zero;
    f16x8 vp = (rowok && w8 < 7) ? *(const f16x8*)&qrow[h * 64 + w8 * 8 + 8] : zero;
#pragma unroll
    for (int djx = 0; djx < 5; ++djx) {
      const int s = djx - 2;
      f16x8 r;
#pragma unroll
      for (int j = 0; j < 8; ++j) {
        const int rel = j + s;
        r[j] = (rel < 0) ? vm[8 + rel] : ((rel < 8) ? vc[rel] : vp[rel - 8]);
      }
      *(f16x8*)(dst + (size_t)djx * (64 * 4352) + hr * 64 + w8 * 8) = r;
    }
  }
}

// ---------------- Kernel 2: attn, all-5-dix-per-block, reuse-maximal -------
// grid 80 = XCD-swizzled (b, djx); block 512 = 8 waves (4 co16-groups x 2
// ci32-halves). attn[d][co][ci] = sum_u k[co][u-64d] * qpad[djx][ci][u]:
// one u-sweep (136 steps) feeds all 5 dix via a 13-slot register af ring
// (af loads contiguous 1KB from frag-major ka2), bf from double-buffered
// XOR-swizzled LDS chunks staged with 128B-run coalesced loads. 20 MFMA per
// 3 loads (was 4 per 5 scattered gathers). Disjoint wave outputs -> plain
// stores, zero merge, zero atomics.
__global__ __launch_bounds__(512) void k_attn(const _Float16* __restrict__ qkh,
                                              const _Float16* __restrict__ qpad,
                                              float* __restrict__ attn_p) {
  int blk = blockIdx.x;             // 80
  int xcd = blk & 7, j = blk >> 3;  // j 0..9
  int b = xcd + ((j >= 5) ? 8 : 0);
  int djx = (j >= 5) ? (j - 5) : j;
  int tid = threadIdx.x, w = tid >> 6, lane = tid & 63;
  int n16 = lane & 15, quad = lane >> 4;
  int g = w & 3, cih = w >> 2;

  __shared__ __align__(16) _Float16 qs[2][64 * 128];  // 32 KB double-buffer

  const _Float16* kaw = qkh + (size_t)(b * 128 + 64) * HW2 + (size_t)g * 65536 +
                        lane * 8;
  const _Float16* qpb = qpad + (size_t)((b * 5 + djx) * 64) * 4352;

  // staging assignment: 8 threads per ci-row, 16B x2 each (128B runs/instr)
  int srow = tid >> 3, sch = (tid & 7) * 2;
  const _Float16* qsrc = qpb + (size_t)srow * 4352 + sch * 8;
  int so0 = srow * 128 + ((sch ^ (srow & 15)) * 8);
  int so1 = srow * 128 + (((sch + 1) ^ (srow & 15)) * 8);

  f32x4 acc[5][2];
#pragma unroll
  for (int d = 0; d < 5; ++d)
#pragma unroll
    for (int nt = 0; nt < 2; ++nt) acc[d][nt] = (f32x4){0.f, 0.f, 0.f, 0.f};

  f16x8 ring[13];
#pragma unroll
  for (int p = 0; p < 4; ++p) ring[p] = *(const f16x8*)(kaw + p * 512);

  // stage chunk 0
  f16x8 sA = *(const f16x8*)(qsrc);
  f16x8 sB = *(const f16x8*)(qsrc + 8);
  *(f16x8*)&qs[0][so0] = sA;
  *(f16x8*)&qs[0][so1] = sB;
  __syncthreads();

#pragma unroll
  for (int c = 0; c < 34; ++c) {
    if (c < 33) {  // issue-early next-chunk loads
      sA = *(const f16x8*)(qsrc + (c + 1) * 128);
      sB = *(const f16x8*)(qsrc + (c + 1) * 128 + 8);
    }
#pragma unroll
    for (int ss = 0; ss < 4; ++ss) {
      const int S = c * 4 + ss;
      if (S + 4 <= 127)
        ring[(S + 4) % 13] = *(const f16x8*)(kaw + (S + 4) * 512);
      const _Float16* qb = qs[c & 1];
      const int chs = ((ss * 4 + quad) ^ n16) * 8;
      f16x8 bf0 = *(const f16x8*)&qb[(cih * 32 + n16) * 128 + chs];
      f16x8 bf1 = *(const f16x8*)&qb[(cih * 32 + 16 + n16) * 128 + chs];
#pragma unroll
      for (int d = 0; d < 5; ++d)
        if (S >= 2 * d && S <= 2 * d + 127) {
          acc[d][0] = __builtin_amdgcn_mfma_f32_16x16x32_f16(
              ring[(S - 2 * d) % 13], bf0, acc[d][0], 0, 0, 0);
          acc[d][1] = __builtin_amdgcn_mfma_f32_16x16x32_f16(
              ring[(S - 2 * d) % 13], bf1, acc[d][1], 0, 0, 0);
        }
    }
    if (c < 33) {  // write-late + single barrier per chunk
      *(f16x8*)&qs[(c + 1) & 1][so0] = sA;
      *(f16x8*)&qs[(c + 1) & 1][so1] = sB;
      __syncthreads();
    }
  }

#pragma unroll
  for (int d = 0; d < 5; ++d) {
    float* op = attn_p + (size_t)(b * 25 + d * 5 + djx) * 4096;
#pragma unroll
    for (int nt = 0; nt < 2; ++nt)
#pragma unroll
      for (int reg = 0; reg < 4; ++reg)
        op[(g * 16 + quad * 4 + reg) * 64 + cih * 32 + nt * 16 + n16] =
            acc[d][nt][reg];
  }
}

// ---------------- Kernel 3: ak_t = valid-conv(attn, weight) ----------------
__global__ __launch_bounds__(576) void k_akconv(const float* __restrict__ attn_p,
                                                const float* __restrict__ wgt,
                                                float* __restrict__ akt) {
  int blk = blockIdx.x;
  int b = blk >> 6, co = blk & 63;
  __shared__ float sa[64 * 25];
  int tid = threadIdx.x;
  for (int e = tid; e < 1600; e += 576) {
    int didj = e >> 6, ci = e & 63;
    size_t idx = (((size_t)b * 25 + didj) * 64 + co) * 64 + ci;
    sa[ci * 25 + didj] = attn_p[idx];
  }
  __syncthreads();
  int o = tid / 9, rs = tid % 9;
  int ki = rs / 3, kj = rs % 3;
  float acc = 0.f;
  for (int ci = 0; ci < 64; ++ci) {
    const float* wp = wgt + (o * 64 + ci) * 9;
    const float* ap = sa + ci * 25 + ki * 5 + kj;
#pragma unroll
    for (int r = 0; r < 3; ++r)
#pragma unroll
      for (int s = 0; s < 3; ++s) acc += ap[r * 5 + s] * wp[r * 3 + s];
  }
  akt[((size_t)(b * 64 + o) * 64 + co) * 9 + rs] = acc;
}

// ---------------- Kernel 4: per-(b,o) norm + fp16 kern assembly ------------
__global__ __launch_bounds__(576) void k_kern(const float* __restrict__ akt,
                                              const float* __restrict__ wgt,
                                              const float* __restrict__ temp,
                                              _Float16* __restrict__ kh) {
  int blk = blockIdx.x;
  int o = blk & 63;
  int tid = threadIdx.x;
  float v = akt[(size_t)blk * 576 + tid];
  float sq = v * v;
#pragma unroll
  for (int m = 1; m < 64; m <<= 1) sq += __shfl_xor(sq, m, 64);
  __shared__ float wsum[9];
  if ((tid & 63) == 0) wsum[tid >> 6] = sq;
  __syncthreads();
  float tot = 0.f;
#pragma unroll
  for (int i = 0; i < 9; ++i) tot += wsum[i];
  float inv = temp[0] / fmaxf(sqrtf(tot), 1e-12f);
  float kv = wgt[o * 576 + tid] + v * inv;
  int b = blk >> 6;
  int ci = tid / 9, rs = tid % 9;
  kh[(((size_t)(b * 9 + rs) * 64 + o) * 64) + ci] = (_Float16)kv;
}

// ---------------- Kernel 5: dynamic 3x3 conv + ReLU, LDS-staged x tile -----
__global__ __launch_bounds__(256, 3) void k_final(const _Float16* __restrict__ xh,
                                                  const _Float16* __restrict__ kh,
                                                  float* __restrict__ out) {
  int blk = blockIdx.x;
  int xt = blk % 3;
  int t2 = blk / 3;
  int yt = t2 % 48, b = t2 / 48;
  int y0 = yt * 4, x0 = xt * 64;

  __shared__ __align__(16) _Float16 xs[6 * 68 * 64];  // 52,224 B -> 3 blocks/CU

  int tid = threadIdx.x;
  int w = tid >> 6, lane = tid & 63;
  int n16 = lane & 15, quad = lane >> 4;

  const _Float16* xb = xh + (size_t)b * (XPH * XPW * 64);
  const _Float16* kb = kh + (size_t)b * (9 * 64 * 64);

  {
    f16x8 v[13];
#pragma unroll
    for (int i = 0; i < 13; ++i) {
      int e = tid + 256 * i;
      if (e < 3264) {
        int row = e / 544, rem = e % 544;
        int px = rem >> 3, c = rem & 7;
        v[i] = *(const f16x8*)(xb + ((size_t)(y0 + row) * XPW + x0 + px) * 64 +
                               c * 8);
      }
    }
#pragma unroll
    for (int i = 0; i < 13; ++i) {
      int e = tid + 256 * i;
      if (e < 3264) {
        int row = e / 544, rem = e % 544;
        int px = rem >> 3, c = rem & 7;
        *(f16x8*)&xs[((row * 68 + px) * 8 + (c ^ (px & 7))) * 8] = v[i];
      }
    }
  }
  __syncthreads();

  f32x4 acc[4][4];
#pragma unroll
  for (int mt = 0; mt < 4; ++mt)
#pragma unroll
    for (int nt = 0; nt < 4; ++nt) acc[mt][nt] = (f32x4){0.f, 0.f, 0.f, 0.f};

#define LDAF(dst, ch_)                                                          \
  {                                                                             \
    const int rs_ = (ch_) >> 1, hi_ = (ch_)&1;                                  \
    _Pragma("unroll") for (int mt = 0; mt < 4; ++mt) dst[mt] =                  \
        *(const f16x8*)(kb + ((size_t)rs_ * 64 + mt * 16 + n16) * 64 +          \
                        hi_ * 32 + quad * 8);                                   \
  }

  f16x8 af[3][4];
  LDAF(af[0], 0)
  LDAF(af[1], 1)

#pragma unroll
  for (int ch = 0; ch < 18; ++ch) {
    if (ch + 2 < 18) LDAF(af[(ch + 2) % 3], ch + 2)
    int rs = ch >> 1, hi = ch & 1;
    int r = rs / 3, s = rs % 3;
    int trow = w + r;  // tile row 0..5
    f16x8 bf[4];
#pragma unroll
    for (int nt = 0; nt < 4; ++nt) {
      int px = nt * 16 + n16 + s;  // 0..65
      int c = (hi * 4 + quad) ^ (px & 7);
      bf[nt] = *(const f16x8*)&xs[((trow * 68 + px) * 8 + c) * 8];
    }
#pragma unroll
    for (int mt = 0; mt < 4; ++mt)
#pragma unroll
      for (int nt = 0; nt < 4; ++nt)
        acc[mt][nt] = __builtin_amdgcn_mfma_f32_16x16x32_f16(af[ch % 3][mt],
                                                             bf[nt], acc[mt][nt],
                                                             0, 0, 0);
  }
#undef LDAF

  int y = y0 + w;
#pragma unroll
  for (int mt = 0; mt < 4; ++mt)
#pragma unroll
    for (int reg = 0; reg < 4; ++reg) {
      int o = mt * 16 + quad * 4 + reg;
      float* op = out + (((size_t)(b * 64 + o) * HH + y) * WW + x0);
#pragma unroll
      for (int nt = 0; nt < 4; ++nt)
        op[nt * 16 + n16] = fmaxf(acc[mt][nt][reg], 0.f);
    }
}

extern "C" void kernel_launch(void* const* d_in, const int* in_sizes, int n_in,
                              void* d_out, int out_size, void* d_ws, size_t ws_size,
                              hipStream_t stream) {
  const float* x = (const float*)d_in[0];     // (16,64,192,192)
  const float* wqk = (const float*)d_in[1];   // (128,64,3,3)
  const float* wgt = (const float*)d_in[2];   // (64,64,3,3)
  const float* temp = (const float*)d_in[3];  // (1,1,1)
  float* out = (float*)d_out;
  char* ws = (char*)d_ws;

  // Workspace layout (bytes):
  _Float16* xh = (_Float16*)ws;                        // 77,873,152 (16*194*196*64*2)
  _Float16* qkh = (_Float16*)(ws + 77873152);          // 16,777,216 (q rows + ka2)
  _Float16* qpad = (_Float16*)(ws + 94650368);         // 44,564,480
  float* attn_p = (float*)(ws + 139214848);            //  6,553,600 (write-once)
  // wh aliases the qpad tail: dead before k_qpad writes qpad.
  _Float16* wh = (_Float16*)(ws + 139067392);          //    147,456
  // akt/kh alias the qpad head (qpad dead after k_attn):
  float* akt = (float*)(ws + 94650368);                //  2,359,296
  _Float16* kh = (_Float16*)(ws + 97009664);           //  1,179,648
  // total 145,768,448 B (~145.8 MB)

  k_wpack<<<dim3(72), 1024, 0, stream>>>(wqk, wh);
  k_xhalo<<<dim3(580), 256, 0, stream>>>(xh);
  k_xpack<<<dim3(9216), 256, 0, stream>>>(x, xh);
  k_qkconv<<<dim3(512), 256, 0, stream>>>(xh, wh, qkh);
  k_qpad<<<dim3(1024), 256, 0, stream>>>(qkh, qpad);
  k_attn<<<dim3(80), 512, 0, stream>>>(qkh, qpad, attn_p);
  k_akconv<<<dim3(1024), 576, 0, stream>>>(attn_p, wgt, akt);
  k_kern<<<dim3(1024), 576, 0, stream>>>(akt, wgt, temp, kh);
  k_final<<<dim3(2304), 256, 0, stream>>>(xh, kh, out);
}